// Round 18
// baseline (164.118 us; speedup 1.0000x reference)
//
#include <hip/hip_runtime.h>

// Shapes: (4, 1, 128, 128, 128) fp32. Elem strides: w=1, h=128, d=16384, n=2097152.
// Round-18: brick tiling. Block = 8d x 8h x 16w elements (256 float4), u staged in
// LDS; halo neighbors read from LDS interior / predicated global at brick faces.
// Goal: cut L2-miss (L3) traffic from ~3x u to ~1.4x u (theory: fk is L3-BW-bound
// at ~5.2 TB/s; round-17 showed occupancy/HBM/unroll invariance).
// Grid = 4n x 16dc x 16hc x 8wc = 8192 blocks.

#define NUM_BLOCKS   8192
#define INV_N        (1.0f / 8388608.0f)

typedef float floatx4 __attribute__((ext_vector_type(4)));

__device__ __forceinline__ floatx4 load4(const float* p) {
    return *reinterpret_cast<const floatx4*>(p);
}

__global__ __launch_bounds__(256) void fk_loss_kernel(
    const float* __restrict__ u,
    const float* __restrict__ dudt,
    const float* __restrict__ D,
    const float* __restrict__ rho,
    float* __restrict__ partials)
{
    const int bid = blockIdx.x;
    const int wc = bid & 7;          // w-chunk (16 floats each)
    const int hc = (bid >> 3) & 15;  // h-chunk (8 rows)
    const int dc = (bid >> 7) & 15;  // d-chunk (8 planes)
    const int n  = bid >> 11;        // batch

    const int tid = threadIdx.x;
    const int w4 = tid & 3;          // f4 within w-chunk
    const int r  = (tid >> 2) & 7;   // row within h-chunk
    const int dl = tid >> 5;         // plane within d-chunk

    const int wf4 = wc * 4 + w4;     // global f4 index in row (0..31)
    const int h   = hc * 8 + r;      // 0..127
    const int d   = dc * 8 + dl;     // 0..127

    const long base = (long)n * 2097152 + (long)d * 16384 + h * 128 + wf4 * 4;

    const floatx4 c  = load4(u    + base);
    const floatx4 dd = load4(dudt + base);
    const floatx4 Dv = load4(D    + base);
    const floatx4 rv = load4(rho  + base);

    __shared__ floatx4 us[256];      // brick's u, 4 KB
    us[tid] = c;
    __syncthreads();

    const floatx4 zero = (floatx4)(0.f);

    // d +/- 1: interior from LDS, faces from global (zero at volume edges)
    floatx4 dm, dp;
    if (dl > 0)      dm = us[tid - 32];
    else             dm = (d == 0)   ? zero : load4(u + base - 16384);
    if (dl < 7)      dp = us[tid + 32];
    else             dp = (d == 127) ? zero : load4(u + base + 16384);

    // h +/- 1
    floatx4 hm, hp;
    if (r > 0)       hm = us[tid - 4];
    else             hm = (h == 0)   ? zero : load4(u + base - 128);
    if (r < 7)       hp = us[tid + 4];
    else             hp = (h == 127) ? zero : load4(u + base + 128);

    // w +/- 1 (scalar)
    float left, right;
    if (w4 > 0)      left  = us[tid - 1].w;
    else             left  = (wf4 == 0)  ? 0.f : u[base - 1];
    if (w4 < 3)      right = us[tid + 1].x;
    else             right = (wf4 == 31) ? 0.f : u[base + 4];

    // 7-point Laplacian (VOXEL_SPACING = 1)
    float lap[4];
    lap[0] = left + c.y + hm.x + hp.x + dm.x + dp.x - 6.0f * c.x;
    lap[1] = c.x  + c.z + hm.y + hp.y + dm.y + dp.y - 6.0f * c.y;
    lap[2] = c.y  + c.w + hm.z + hp.z + dm.z + dp.z - 6.0f * c.z;
    lap[3] = c.z + right + hm.w + hp.w + dm.w + dp.w - 6.0f * c.w;

    const float cc[4]  = {c.x, c.y, c.z, c.w};
    const float dda[4] = {dd.x, dd.y, dd.z, dd.w};
    const float Da[4]  = {Dv.x, Dv.y, Dv.z, Dv.w};
    const float ra[4]  = {rv.x, rv.y, rv.z, rv.w};

    float partial = 0.f;
#pragma unroll
    for (int i = 0; i < 4; ++i) {
        const float reaction = ra[i] * cc[i] * (1.0f - cc[i]);
        const float residual = dda[i] - (Da[i] * lap[i] + reaction);
        partial += residual * residual;
    }

    // Wave-64 reduction
#pragma unroll
    for (int off = 32; off > 0; off >>= 1)
        partial += __shfl_down(partial, off);

    __shared__ float smem[4];   // 256 threads = 4 waves
    const int lane = tid & 63;
    const int wid  = tid >> 6;
    if (lane == 0) smem[wid] = partial;
    __syncthreads();

    if (tid == 0)
        partials[bid] = (smem[0] + smem[1]) + (smem[2] + smem[3]);
}

// Stage 2: one block sums NUM_BLOCKS partials, writes out.
__global__ __launch_bounds__(1024) void fk_reduce_kernel(
    const float* __restrict__ partials, float* __restrict__ out)
{
    float s = 0.f;
#pragma unroll
    for (int i = 0; i < NUM_BLOCKS / 1024; ++i)
        s += partials[threadIdx.x + i * 1024];

#pragma unroll
    for (int off = 32; off > 0; off >>= 1)
        s += __shfl_down(s, off);

    __shared__ float smem[16];   // 1024 threads = 16 waves
    const int lane = threadIdx.x & 63;
    const int wid  = threadIdx.x >> 6;
    if (lane == 0) smem[wid] = s;
    __syncthreads();

    if (threadIdx.x == 0) {
        float t = 0.f;
#pragma unroll
        for (int i = 0; i < 16; ++i) t += smem[i];
        out[0] = t * INV_N;
    }
}

extern "C" void kernel_launch(void* const* d_in, const int* in_sizes, int n_in,
                              void* d_out, int out_size, void* d_ws, size_t ws_size,
                              hipStream_t stream) {
    const float* u    = (const float*)d_in[0];
    const float* dudt = (const float*)d_in[1];
    const float* D    = (const float*)d_in[2];
    const float* rho  = (const float*)d_in[3];
    float* out      = (float*)d_out;
    float* partials = (float*)d_ws;   // 8192 floats = 32 KB scratch

    fk_loss_kernel<<<NUM_BLOCKS, 256, 0, stream>>>(u, dudt, D, rho, partials);
    fk_reduce_kernel<<<1, 1024, 0, stream>>>(partials, out);
}